// Round 4
// baseline (715.723 us; speedup 1.0000x reference)
//
#include <hip/hip_runtime.h>

#define N_NODES 50000
#define N_EDGES 1600000
#define IN_FEATS 128
#define N_HIDDEN 256
#define N_CLASSES 41
#define CHW 16                 // chunk width (floats) = 64 B
#define NCHUNK0 8              // 128/16
#define NCHUNK1 3              // 48/16 (41 padded)
#define NB_G 782               // ceil(50000/64) node-blocks for gathers
#define ECAP 1024              // staged edge indices per wave

// -------- workspace layout (bytes) --------
#define IDEG_OFF 0             // N_NODES int
#define ROWS_OFF 204800        // N_NODES+1 int
#define CURS_OFF 409600        // N_NODES int
#define ESRC_OFF 614400        // N_EDGES int (6.4 MB)
#define ACC0_OFF 7014400       // [8][N_NODES][16] f32 (25.6 MB); y1 aliases chunks 0..2
#define PBUF_OFF 32614400      // rotating packed chunk, 3.2 MB (optional)
#define PBUF_BYTES 3200000

__global__ void deg_kernel(const int* __restrict__ dst, int* __restrict__ ideg) {
    int e = blockIdx.x * blockDim.x + threadIdx.x;
    if (e < N_EDGES) atomicAdd(&ideg[dst[e]], 1);
}

#define SCAN_THREADS 1024
#define SCAN_CHUNK ((N_NODES + SCAN_THREADS - 1) / SCAN_THREADS)   // 49
__global__ __launch_bounds__(SCAN_THREADS) void scan_kernel(
        const int* __restrict__ ideg, int* __restrict__ row_start,
        int* __restrict__ cursor) {
    __shared__ int part[SCAN_THREADS];
    int t = threadIdx.x;
    int lo = t * SCAN_CHUNK;
    int hi = min(lo + SCAN_CHUNK, N_NODES);
    int s = 0;
    for (int i = lo; i < hi; ++i) s += ideg[i];
    part[t] = s;
    __syncthreads();
    for (int off = 1; off < SCAN_THREADS; off <<= 1) {
        int v = (t >= off) ? part[t - off] : 0;
        __syncthreads();
        if (t >= off) part[t] += v;
        __syncthreads();
    }
    int run = (t == 0) ? 0 : part[t - 1];
    for (int i = lo; i < hi; ++i) {
        row_start[i] = run;
        cursor[i] = run;
        run += ideg[i];
    }
    if (t == SCAN_THREADS - 1) row_start[N_NODES] = part[SCAN_THREADS - 1];
}

__global__ void fill_csr(const int* __restrict__ src, const int* __restrict__ dst,
                         int* __restrict__ cursor, int* __restrict__ edge_src) {
    int e = blockIdx.x * blockDim.x + threadIdx.x;
    if (e >= N_EDGES) return;
    int d = dst[e];
    int p = atomicAdd(&cursor[d], 1);
    edge_src[p] = src[e];
}

// repack one 16-float column chunk contiguously: pbuf[n*16+j] = feat[n*128 + c*16 + j]
__global__ void repack_chunk(const float* __restrict__ feat, int c,
                             float* __restrict__ pbuf) {
    int p = blockIdx.x * 256 + threadIdx.x;      // < 800000
    int n = p >> 4, j = p & 15;
    pbuf[p] = feat[(size_t)n * IN_FEATS + c * CHW + j];
}

// gather one 16-float chunk for 64 nodes/block: wave = 16 nodes x 4 lanes (float4/lane)
// element address: fbase + coff + idx*fstride + l4*4
__global__ __launch_bounds__(256) void gather0(
        const float* __restrict__ fbase, int fstride, int coff, int chunk,
        const int* __restrict__ row_start, const int* __restrict__ edge_src,
        float* __restrict__ acc0) {
    __shared__ int eidx[4][ECAP];
    const int t = threadIdx.x;
    const int w = t >> 6, lane = t & 63;
    const int g = lane >> 2, l4 = lane & 3;
    const int n0w = blockIdx.x * 64 + w * 16;

    int v = row_start[min(n0w + lane, N_NODES)];
    const int gbase = __shfl(v, 0);
    const int sg = __shfl(v, g);
    const int cnt = __shfl(v, g + 1) - sg;
    const int sl = sg - gbase;
    const int tot = __shfl(v, 16) - gbase;

    for (int i = lane; i < min(tot, ECAP); i += 64)
        eidx[w][i] = edge_src[gbase + i];
    __syncthreads();

    int maxc = cnt;
#pragma unroll
    for (int off = 32; off; off >>= 1) maxc = max(maxc, __shfl_xor(maxc, off));

    const float* fp = fbase + coff + l4 * 4;
    float4 a0 = make_float4(0.f, 0.f, 0.f, 0.f);
    float4 a1 = make_float4(0.f, 0.f, 0.f, 0.f);
    for (int k = 0; k < maxc; k += 2) {
        if (k < cnt) {
            int p = sl + k;
            int idx = (p < ECAP) ? eidx[w][p] : edge_src[gbase + p];
            float4 vv = *(const float4*)(fp + (size_t)idx * fstride);
            a0.x += vv.x; a0.y += vv.y; a0.z += vv.z; a0.w += vv.w;
        }
        if (k + 1 < cnt) {
            int p = sl + k + 1;
            int idx = (p < ECAP) ? eidx[w][p] : edge_src[gbase + p];
            float4 vv = *(const float4*)(fp + (size_t)idx * fstride);
            a1.x += vv.x; a1.y += vv.y; a1.z += vv.z; a1.w += vv.w;
        }
    }
    a0.x += a1.x; a0.y += a1.y; a0.z += a1.z; a0.w += a1.w;
    const int node = n0w + g;
    if (node < N_NODES)
        *(float4*)(acc0 + ((size_t)chunk * N_NODES + node) * CHW + l4 * 4) = a0;
}

// fused MLP: x = acc0[node]/deg (chunk-major); h = relu(x@W1+b1); y1 = h@W2
// y1 written chunk-major into acc0 chunks 0..2 (aliased; reads complete first)
#define NPB 16
#define HS_LD 260
__global__ __launch_bounds__(256) void mlp(
        const float* __restrict__ acc0, const int* __restrict__ ideg,
        const float* __restrict__ W1, const float* __restrict__ b1,
        const float* __restrict__ W2, float* __restrict__ y1) {
    __shared__ float xs[NPB][IN_FEATS];
    __shared__ float hs[NPB][HS_LD];
    __shared__ float sinv[NPB];
    const int t = threadIdx.x;
    const int node0 = blockIdx.x * NPB;
    if (t < NPB) sinv[t] = 1.0f / fmaxf((float)ideg[node0 + t], 1.0f);
    __syncthreads();

#pragma unroll
    for (int r = 0; r < 8; ++r) {
        int p = r * 256 + t;                  // 0..2047
        int nl = p >> 7, f = p & 127;
        int c = f >> 4, j = f & 15;
        xs[nl][f] = acc0[((size_t)c * N_NODES + node0 + nl) * CHW + j] * sinv[nl];
    }
    __syncthreads();

    float acc[NPB];
    float bb = b1[t];
#pragma unroll
    for (int nl = 0; nl < NPB; ++nl) acc[nl] = bb;
    for (int k = 0; k < IN_FEATS; k += 4) {
        float w0 = W1[(k + 0) * N_HIDDEN + t];
        float w1 = W1[(k + 1) * N_HIDDEN + t];
        float w2 = W1[(k + 2) * N_HIDDEN + t];
        float w3 = W1[(k + 3) * N_HIDDEN + t];
#pragma unroll
        for (int nl = 0; nl < NPB; ++nl) {
            const float4 xv = *(const float4*)&xs[nl][k];
            acc[nl] = fmaf(xv.x, w0, acc[nl]);
            acc[nl] = fmaf(xv.y, w1, acc[nl]);
            acc[nl] = fmaf(xv.z, w2, acc[nl]);
            acc[nl] = fmaf(xv.w, w3, acc[nl]);
        }
    }
#pragma unroll
    for (int nl = 0; nl < NPB; ++nl) hs[nl][t] = fmaxf(acc[nl], 0.0f);
    __syncthreads();

    // GEMM2: 16 groups of 16 lanes; group nl -> node, lane j -> cols {j, 16+j, 32+j}
    const int nl2 = t >> 4, j2 = t & 15;
    const int c2 = (j2 < 9) ? (32 + j2) : 32;     // clamped, discarded if j2>=9
    float s0 = 0.f, s1 = 0.f, s2 = 0.f;
    for (int k = 0; k < N_HIDDEN; ++k) {
        float h = hs[nl2][k];
        s0 = fmaf(h, W2[k * N_CLASSES + j2], s0);
        s1 = fmaf(h, W2[k * N_CLASSES + 16 + j2], s1);
        s2 = fmaf(h, W2[k * N_CLASSES + c2], s2);
    }
    const int node = node0 + nl2;
    y1[((size_t)0 * N_NODES + node) * CHW + j2] = s0;
    y1[((size_t)1 * N_NODES + node) * CHW + j2] = s1;
    y1[((size_t)2 * N_NODES + node) * CHW + j2] = (j2 < 9) ? s2 : 0.0f;
}

// second aggregation over y1 (chunk-major), epilogue: /deg + b2, col-guarded stores
__global__ __launch_bounds__(256) void gather1(
        const float* __restrict__ y1, int chunk,
        const int* __restrict__ row_start, const int* __restrict__ edge_src,
        const float* __restrict__ b2, float* __restrict__ out) {
    __shared__ int eidx[4][ECAP];
    const int t = threadIdx.x;
    const int w = t >> 6, lane = t & 63;
    const int g = lane >> 2, l4 = lane & 3;
    const int n0w = blockIdx.x * 64 + w * 16;

    int v = row_start[min(n0w + lane, N_NODES)];
    const int gbase = __shfl(v, 0);
    const int sg = __shfl(v, g);
    const int cnt = __shfl(v, g + 1) - sg;
    const int sl = sg - gbase;
    const int tot = __shfl(v, 16) - gbase;

    for (int i = lane; i < min(tot, ECAP); i += 64)
        eidx[w][i] = edge_src[gbase + i];
    __syncthreads();

    int maxc = cnt;
#pragma unroll
    for (int off = 32; off; off >>= 1) maxc = max(maxc, __shfl_xor(maxc, off));

    const float* fp = y1 + (size_t)chunk * N_NODES * CHW + l4 * 4;
    float4 a0 = make_float4(0.f, 0.f, 0.f, 0.f);
    float4 a1 = make_float4(0.f, 0.f, 0.f, 0.f);
    for (int k = 0; k < maxc; k += 2) {
        if (k < cnt) {
            int p = sl + k;
            int idx = (p < ECAP) ? eidx[w][p] : edge_src[gbase + p];
            float4 vv = *(const float4*)(fp + (size_t)idx * CHW);
            a0.x += vv.x; a0.y += vv.y; a0.z += vv.z; a0.w += vv.w;
        }
        if (k + 1 < cnt) {
            int p = sl + k + 1;
            int idx = (p < ECAP) ? eidx[w][p] : edge_src[gbase + p];
            float4 vv = *(const float4*)(fp + (size_t)idx * CHW);
            a1.x += vv.x; a1.y += vv.y; a1.z += vv.z; a1.w += vv.w;
        }
    }
    const int node = n0w + g;
    if (node < N_NODES) {
        float invd = 1.0f / fmaxf((float)cnt, 1.0f);
        float r[4] = {a0.x + a1.x, a0.y + a1.y, a0.z + a1.z, a0.w + a1.w};
        const int cbase = chunk * CHW + l4 * 4;
#pragma unroll
        for (int i = 0; i < 4; ++i) {
            int col = cbase + i;
            if (col < N_CLASSES)
                out[(size_t)node * N_CLASSES + col] = r[i] * invd + b2[col];
        }
    }
}

extern "C" void kernel_launch(void* const* d_in, const int* in_sizes, int n_in,
                              void* d_out, int out_size, void* d_ws, size_t ws_size,
                              hipStream_t stream) {
    const float* feat = (const float*)d_in[0];
    const int*   src  = (const int*)d_in[1];
    const int*   dst  = (const int*)d_in[2];
    const float* W1   = (const float*)d_in[3];
    const float* b1   = (const float*)d_in[4];
    const float* W2   = (const float*)d_in[5];
    const float* b2   = (const float*)d_in[6];
    float* out = (float*)d_out;

    char* ws = (char*)d_ws;
    int*   ideg      = (int*)(ws + IDEG_OFF);
    int*   row_start = (int*)(ws + ROWS_OFF);
    int*   cursor    = (int*)(ws + CURS_OFF);
    int*   edge_src  = (int*)(ws + ESRC_OFF);
    float* acc0      = (float*)(ws + ACC0_OFF);
    float* pbuf      = (float*)(ws + PBUF_OFF);
    float* y1        = acc0;   // y1 aliases acc0 chunks 0..2

    hipMemsetAsync(ideg, 0, N_NODES * 4, stream);
    deg_kernel<<<(N_EDGES + 255) / 256, 256, 0, stream>>>(dst, ideg);
    scan_kernel<<<1, SCAN_THREADS, 0, stream>>>(ideg, row_start, cursor);
    fill_csr<<<(N_EDGES + 255) / 256, 256, 0, stream>>>(src, dst, cursor, edge_src);

    const bool useP = (ws_size >= (size_t)PBUF_OFF + PBUF_BYTES);
    for (int c = 0; c < NCHUNK0; ++c) {
        if (useP) {
            repack_chunk<<<(N_NODES * CHW) / 256, 256, 0, stream>>>(feat, c, pbuf);
            gather0<<<NB_G, 256, 0, stream>>>(pbuf, CHW, 0, c, row_start, edge_src, acc0);
        } else {
            gather0<<<NB_G, 256, 0, stream>>>(feat, IN_FEATS, c * CHW, c, row_start,
                                              edge_src, acc0);
        }
    }

    mlp<<<N_NODES / NPB, 256, 0, stream>>>(acc0, ideg, W1, b1, W2, y1);

    for (int c = 0; c < NCHUNK1; ++c)
        gather1<<<NB_G, 256, 0, stream>>>(y1, c, row_start, edge_src, b2, out);
}